// Round 6
// baseline (793.202 us; speedup 1.0000x reference)
//
#include <hip/hip_runtime.h>
#include <hip/hip_bf16.h>

typedef unsigned short u16;
typedef __bf16 bf16x8 __attribute__((ext_vector_type(8)));
typedef float  f32x4  __attribute__((ext_vector_type(4)));

#define N_  16384
#define SCALE_ 0.125f
#define TILE 128
#define TPAD 66

__device__ __forceinline__ u16 f2b(float f){
  unsigned u = __float_as_uint(f);
  unsigned r = (u + 0x7fffu + ((u>>16)&1u)) >> 16;
  return (u16)r;
}
__device__ __forceinline__ float blo(unsigned u){ return __uint_as_float(u<<16); }
__device__ __forceinline__ float bhi(unsigned u){ return __uint_as_float(u & 0xffff0000u); }
__device__ __forceinline__ void ld8(const float* __restrict__ p, float* f){
  const float4 a = ((const float4*)p)[0];
  const float4 b = ((const float4*)p)[1];
  f[0]=a.x; f[1]=a.y; f[2]=a.z; f[3]=a.w;
  f[4]=b.x; f[5]=b.y; f[6]=b.z; f[7]=b.w;
}
__device__ __forceinline__ bf16x8 frag8(const float* __restrict__ p){
  float f[8]; ld8(p, f);
  bf16x8 r;
  #pragma unroll
  for (int j=0;j<8;++j) r[j] = (__bf16)f[j];
  return r;
}

// ---------------- diagnostic marker (fp32 out) ----------------
__global__ __launch_bounds__(256) void k_marker(float* __restrict__ out, int n, float val){
  const int i = blockIdx.x*256 + threadIdx.x;
  if (i < n) out[i] = val;
}

// ---------------- slots init: mu + sigma * noise ----------------
__global__ __launch_bounds__(256) void k_init_slots(
  const float* __restrict__ mu, const float* __restrict__ sigma,
  const float* __restrict__ noise, float* __restrict__ slots)
{
  const int idx = blockIdx.x*256 + threadIdx.x;   // grid 56*256 = 14336 exact
  const int d = idx & 63;
  slots[idx] = mu[d] + sigma[d] * noise[idx];
}

// ---------------- per-iter: q = ln(slots)@Wq^T + bq; zero accumulators ----------------
__global__ __launch_bounds__(256) void k_qln_zero(
  const float* __restrict__ slots, const float* __restrict__ Wq, const float* __restrict__ bq,
  const float* __restrict__ g_sl, const float* __restrict__ b_sl,
  float* __restrict__ qout, float* __restrict__ num, float* __restrict__ den)
{
  const int tid = blockIdx.x*256 + threadIdx.x;    // grid 56*256 = 14336 exact
  num[tid] = 0.f;
  if (tid < 224) den[tid] = 0.f;
  const int ri = tid >> 6, lane = tid & 63;
  const float xv = slots[ri*64 + lane];
  float s = xv, ss = xv*xv;
  #pragma unroll
  for (int off=1; off<64; off<<=1){ s += __shfl_xor(s,off); ss += __shfl_xor(ss,off); }
  const float mean = s*(1.f/64.f);
  const float rstd = rsqrtf(ss*(1.f/64.f) - mean*mean + 1e-5f);
  const float sn = (xv-mean)*rstd*g_sl[lane] + b_sl[lane];
  float acc = 0.f;
  for (int d8=0; d8<8; ++d8){
    float wf[8]; ld8(Wq + lane*64 + d8*8, wf);
    #pragma unroll
    for (int j=0;j<8;++j) acc += __shfl(sn, d8*8+j) * wf[j];
  }
  qout[ri*64+lane] = acc + bq[lane];
}

// ---------------- fused attention: LN(x) -> k,v (MFMA) -> softmax reduce ----------------
// grid = 32 batches x 64 chunks; each block: 2 tiles of 128 keys.
// A-frag (16x16x32 bf16): lane holds A[m=lane&15][k=(lane>>4)*8 + j (+32 for 2nd half)]
// B-frag: lane holds B[k=(lane>>4)*8+j][n=lane&15]  (B = W^T, so load W[n][k])
// D: lane reg r -> row (lane>>4)*4+r, col lane&15
__global__ __launch_bounds__(256) void k_attn_fused(
  const float* __restrict__ x,
  const float* __restrict__ Wk, const float* __restrict__ bk,
  const float* __restrict__ Wv, const float* __restrict__ bv,
  const float* __restrict__ g_in, const float* __restrict__ b_in,
  const float* __restrict__ qbuf, float* __restrict__ num, float* __restrict__ den)
{
  __shared__ __align__(16) u16   tile[TILE*TPAD];  // 16.9 KB
  __shared__ __align__(16) float qs[7*64];         // 1.8 KB
  __shared__ __align__(16) float at[7*TILE];       // 3.6 KB
  const int t = threadIdx.x;
  const int b = blockIdx.x >> 6, ch = blockIdx.x & 63;
  for (int i=t; i<448; i+=256) qs[i] = qbuf[b*448 + i];
  const int wid = t>>6, lane = t&63;
  const int m = lane & 15, q4 = lane >> 4;
  float gf[16], bfv[16];
  ld8(g_in + q4*8, gf);  ld8(g_in + 32 + q4*8, gf+8);
  ld8(b_in + q4*8, bfv); ld8(b_in + 32 + q4*8, bfv+8);
  const int i0 = wid*2, i1 = wid*2+1;              // wid 3 -> only slot 6
  float n0=0.f, n1=0.f, d0=0.f, d1=0.f;

  for (int tl=0; tl<2; ++tl){
    const long j0 = (long)ch*256 + tl*TILE;
    const long rowbase = (long)b*N_ + j0 + (long)wid*32;
    __syncthreads();                               // b1: tile/at free; qs ready
    // ---- (a) load x rows (fp32), in-register LayerNorm -> bf16 A-frags ----
    bf16x8 af[2][2];
    #pragma unroll
    for (int rg=0; rg<2; ++rg){
      const float* xr = x + (rowbase + rg*16 + m)*64;
      float xf[16];
      ld8(xr + q4*8, xf); ld8(xr + 32 + q4*8, xf+8);
      float s=0.f, ss=0.f;
      #pragma unroll
      for (int i=0;i<16;++i){ s += xf[i]; ss += xf[i]*xf[i]; }
      s  += __shfl_xor(s,16);  s  += __shfl_xor(s,32);
      ss += __shfl_xor(ss,16); ss += __shfl_xor(ss,32);
      const float mean = s*(1.f/64.f);
      const float rstd = rsqrtf(ss*(1.f/64.f) - mean*mean + 1e-5f);
      #pragma unroll
      for (int j=0;j<8;++j){
        af[rg][0][j] = (__bf16)((xf[j]  -mean)*rstd*gf[j]   + bfv[j]);
        af[rg][1][j] = (__bf16)((xf[8+j]-mean)*rstd*gf[8+j] + bfv[8+j]);
      }
    }
    // ---- (b) k = x_ln @ Wk^T + bk -> LDS tile (bf16) ----
    {
      bf16x8 w0[4], w1[4]; float bc[4];
      #pragma unroll
      for (int cg=0; cg<4; ++cg){
        const int n = cg*16 + m;
        w0[cg] = frag8(Wk + n*64 + q4*8);
        w1[cg] = frag8(Wk + n*64 + 32 + q4*8);
        bc[cg] = bk[n];
      }
      #pragma unroll
      for (int rg=0; rg<2; ++rg){
        #pragma unroll
        for (int cg=0; cg<4; ++cg){
          f32x4 acc = {0.f,0.f,0.f,0.f};
          acc = __builtin_amdgcn_mfma_f32_16x16x32_bf16(af[rg][0], w0[cg], acc, 0,0,0);
          acc = __builtin_amdgcn_mfma_f32_16x16x32_bf16(af[rg][1], w1[cg], acc, 0,0,0);
          const int col = cg*16 + m;
          #pragma unroll
          for (int r=0;r<4;++r)
            tile[(wid*32 + rg*16 + q4*4 + r)*TPAD + col] = f2b(acc[r] + bc[cg]);
        }
      }
    }
    __syncthreads();                               // b2: k visible
    // ---- (c) phase A: thread t (<128) owns key j0+t; softmax over slots ----
    if (t < TILE){
      float acc[7];
      #pragma unroll
      for (int i=0;i<7;++i) acc[i]=0.f;
      const unsigned* krow = (const unsigned*)&tile[t*TPAD];
      for (int wq=0; wq<8; ++wq){
        const unsigned k0 = krow[wq*4+0], k1 = krow[wq*4+1], k2 = krow[wq*4+2], k3 = krow[wq*4+3];
        float kf[8];
        kf[0]=blo(k0); kf[1]=bhi(k0); kf[2]=blo(k1); kf[3]=bhi(k1);
        kf[4]=blo(k2); kf[5]=bhi(k2); kf[6]=blo(k3); kf[7]=bhi(k3);
        #pragma unroll
        for (int i=0;i<7;++i){
          const float4 qa = *(const float4*)&qs[i*64 + wq*8];
          const float4 qb = *(const float4*)&qs[i*64 + wq*8 + 4];
          acc[i] += kf[0]*qa.x + kf[1]*qa.y + kf[2]*qa.z + kf[3]*qa.w
                  + kf[4]*qb.x + kf[5]*qb.y + kf[6]*qb.z + kf[7]*qb.w;
        }
      }
      float mx = -1e30f;
      #pragma unroll
      for (int i=0;i<7;++i){ acc[i] *= SCALE_; mx = fmaxf(mx, acc[i]); }
      float e[7]; float sum = 0.f;
      #pragma unroll
      for (int i=0;i<7;++i){ e[i] = __expf(acc[i]-mx); sum += e[i]; }
      const float inv = 1.f/sum;
      #pragma unroll
      for (int i=0;i<7;++i) at[i*TILE + t] = e[i]*inv + 1e-8f;
    }
    __syncthreads();                               // b3: phase A done
    // ---- (d) v = x_ln @ Wv^T + bv -> LDS tile (overwrite k) ----
    {
      bf16x8 w0[4], w1[4]; float bc[4];
      #pragma unroll
      for (int cg=0; cg<4; ++cg){
        const int n = cg*16 + m;
        w0[cg] = frag8(Wv + n*64 + q4*8);
        w1[cg] = frag8(Wv + n*64 + 32 + q4*8);
        bc[cg] = bv[n];
      }
      #pragma unroll
      for (int rg=0; rg<2; ++rg){
        #pragma unroll
        for (int cg=0; cg<4; ++cg){
          f32x4 acc = {0.f,0.f,0.f,0.f};
          acc = __builtin_amdgcn_mfma_f32_16x16x32_bf16(af[rg][0], w0[cg], acc, 0,0,0);
          acc = __builtin_amdgcn_mfma_f32_16x16x32_bf16(af[rg][1], w1[cg], acc, 0,0,0);
          const int col = cg*16 + m;
          #pragma unroll
          for (int r=0;r<4;++r)
            tile[(wid*32 + rg*16 + q4*4 + r)*TPAD + col] = f2b(acc[r] + bc[cg]);
        }
      }
    }
    __syncthreads();                               // b4: v visible
    // ---- (e) phase B: wave -> slots {i0,i1}, lane -> dim ----
    #pragma unroll 4
    for (int j=0;j<TILE;++j){
      const unsigned vw = ((const unsigned*)&tile[j*TPAD])[lane>>1];
      const float vf = (lane&1) ? bhi(vw) : blo(vw);
      const float a0v = at[i0*TILE+j];
      n0 += a0v*vf; d0 += a0v;
      if (i1 < 7){ const float a1v = at[i1*TILE+j]; n1 += a1v*vf; d1 += a1v; }
    }
  }
  atomicAdd(&num[(b*7+i0)*64 + lane], n0);
  if (lane==0) atomicAdd(&den[b*7+i0], d0);
  if (i1 < 7){
    atomicAdd(&num[(b*7+i1)*64 + lane], n1);
    if (lane==0) atomicAdd(&den[b*7+i1], d1);
  }
}

// ---------------- per-iter: updates -> GRU -> residual MLP ----------------
__global__ __launch_bounds__(256) void k_gru_mlp(
  const float* __restrict__ num, const float* __restrict__ den, float* __restrict__ slots,
  const float* __restrict__ Wih, const float* __restrict__ Whh,
  const float* __restrict__ bih, const float* __restrict__ bhh,
  const float* __restrict__ mW1, const float* __restrict__ mb1,
  const float* __restrict__ mW2, const float* __restrict__ mb2,
  const float* __restrict__ g_ml, const float* __restrict__ b_ml,
  float* __restrict__ outp, const int write_out)
{
  const int tid = blockIdx.x*256 + threadIdx.x;  // grid 56*256: 224 waves = 224 rows
  const int ri = tid>>6, lane = tid&63;
  const float dn = den[ri];
  const float u = (dn > 0.f) ? (num[ri*64+lane] / dn) : 0.f;
  const float h = slots[ri*64+lane];
  float air=0,aiz=0,ain=0,ahr=0,ahz=0,ahn=0;
  for (int d8=0; d8<8; ++d8){
    float fir[8],fiz[8],fin[8],fhr[8],fhz[8],fhn[8];
    ld8(Wih + (      lane)*64 + d8*8, fir);
    ld8(Wih + ( 64 + lane)*64 + d8*8, fiz);
    ld8(Wih + (128 + lane)*64 + d8*8, fin);
    ld8(Whh + (      lane)*64 + d8*8, fhr);
    ld8(Whh + ( 64 + lane)*64 + d8*8, fhz);
    ld8(Whh + (128 + lane)*64 + d8*8, fhn);
    #pragma unroll
    for (int j=0;j<8;++j){
      const float ud = __shfl(u, d8*8+j);
      const float hd = __shfl(h, d8*8+j);
      air += ud*fir[j]; aiz += ud*fiz[j]; ain += ud*fin[j];
      ahr += hd*fhr[j]; ahz += hd*fhz[j]; ahn += hd*fhn[j];
    }
  }
  air += bih[lane]; aiz += bih[64+lane]; ain += bih[128+lane];
  ahr += bhh[lane]; ahz += bhh[64+lane]; ahn += bhh[128+lane];
  const float r = 1.f/(1.f + __expf(-(air+ahr)));
  const float z = 1.f/(1.f + __expf(-(aiz+ahz)));
  const float n = tanhf(ain + r*ahn);
  const float sv = (1.f-z)*n + z*h;
  // residual MLP
  float s=sv, ss=sv*sv;
  #pragma unroll
  for (int off=1; off<64; off<<=1){ s += __shfl_xor(s,off); ss += __shfl_xor(ss,off); }
  const float mean = s*(1.f/64.f);
  const float rstd = rsqrtf(ss*(1.f/64.f) - mean*mean + 1e-5f);
  const float m = (sv-mean)*rstd*g_ml[lane] + b_ml[lane];
  float h1a=0.f, h1b=0.f;
  for (int d8=0; d8<8; ++d8){
    float f1[8], f2[8];
    ld8(mW1 + (     lane)*64 + d8*8, f1);
    ld8(mW1 + (64 + lane)*64 + d8*8, f2);
    #pragma unroll
    for (int j=0;j<8;++j){
      const float md = __shfl(m, d8*8+j);
      h1a += md*f1[j]; h1b += md*f2[j];
    }
  }
  h1a = fmaxf(h1a + mb1[lane], 0.f);
  h1b = fmaxf(h1b + mb1[64+lane], 0.f);
  float o = 0.f;
  for (int h8=0; h8<8; ++h8){
    float fa[8], fb[8];
    ld8(mW2 + lane*128 + h8*8, fa);
    ld8(mW2 + lane*128 + 64 + h8*8, fb);
    #pragma unroll
    for (int j=0;j<8;++j){
      o += __shfl(h1a, h8*8+j)*fa[j] + __shfl(h1b, h8*8+j)*fb[j];
    }
  }
  o += mb2[lane];
  const float res = sv + o;
  slots[ri*64+lane] = res;
  if (write_out) outp[ri*64+lane] = res;   // fp32 output
}

extern "C" void kernel_launch(void* const* d_in, const int* in_sizes, int n_in,
                              void* d_out, int out_size, void* d_ws, size_t ws_size,
                              hipStream_t stream)
{
  float* outp = (float*)d_out;   // reference output dtype = float32
  static const int EXP[24] = {33554432,14336,64,64, 4096,64, 4096,64, 4096,64,
                              12288,12288,192,192, 8192,128, 8192,64,
                              64,64, 64,64, 64,64};
  if (n_in != 24){ k_marker<<<56,256,0,stream>>>(outp, out_size, 30.f); return; }
  for (int i=0;i<24;++i)
    if (in_sizes[i] != EXP[i]){ k_marker<<<56,256,0,stream>>>(outp, out_size, 40.f+(float)i); return; }
  if (out_size != 14336){ k_marker<<<56,256,0,stream>>>(outp, out_size, 33.f); return; }
  if (ws_size < 200000){ k_marker<<<56,256,0,stream>>>(outp, out_size, 35.f); return; }

  const float* inputs = (const float*)d_in[0];
  const float* noise  = (const float*)d_in[1];
  const float* mu     = (const float*)d_in[2];
  const float* sigma  = (const float*)d_in[3];
  const float* Wq  = (const float*)d_in[4];  const float* bq  = (const float*)d_in[5];
  const float* Wk  = (const float*)d_in[6];  const float* bk  = (const float*)d_in[7];
  const float* Wv  = (const float*)d_in[8];  const float* bv  = (const float*)d_in[9];
  const float* Wih = (const float*)d_in[10]; const float* Whh = (const float*)d_in[11];
  const float* bih = (const float*)d_in[12]; const float* bhh = (const float*)d_in[13];
  const float* mW1 = (const float*)d_in[14]; const float* mb1 = (const float*)d_in[15];
  const float* mW2 = (const float*)d_in[16]; const float* mb2 = (const float*)d_in[17];
  const float* g_in = (const float*)d_in[18]; const float* b_in = (const float*)d_in[19];
  const float* g_sl = (const float*)d_in[20]; const float* b_sl = (const float*)d_in[21];
  const float* g_ml = (const float*)d_in[22]; const float* b_ml = (const float*)d_in[23];

  char* ws = (char*)d_ws;
  float* slots = (float*)ws;                         // 14336 f
  float* qbuf  = (float*)(ws + 57344);               // 14336 f
  float* num   = (float*)(ws + 114688);              // 14336 f
  float* den   = (float*)(ws + 172032);              // 224 f

  k_init_slots<<<56,256,0,stream>>>(mu, sigma, noise, slots);
  for (int it=0; it<3; ++it){
    k_qln_zero<<<56,256,0,stream>>>(slots, Wq, bq, g_sl, b_sl, qbuf, num, den);
    k_attn_fused<<<2048,256,0,stream>>>(inputs, Wk, bk, Wv, bv, g_in, b_in, qbuf, num, den);
    k_gru_mlp<<<56,256,0,stream>>>(num, den, slots, Wih, Whh, bih, bhh,
                                   mW1, mb1, mW2, mb2, g_ml, b_ml,
                                   outp, it==2 ? 1 : 0);
  }
}

// Round 7
// 547.407 us; speedup vs baseline: 1.4490x; 1.4490x over previous
//
#include <hip/hip_runtime.h>
#include <hip/hip_bf16.h>

typedef unsigned short u16;
typedef __bf16 bf16x8 __attribute__((ext_vector_type(8)));
typedef float  f32x4  __attribute__((ext_vector_type(4)));

#define N_  16384
#define SCALE_ 0.125f
#define TILE 128
#define TPAD 66

__device__ __forceinline__ u16 f2b(float f){
  unsigned u = __float_as_uint(f);
  unsigned r = (u + 0x7fffu + ((u>>16)&1u)) >> 16;
  return (u16)r;
}
__device__ __forceinline__ float blo(unsigned u){ return __uint_as_float(u<<16); }
__device__ __forceinline__ float bhi(unsigned u){ return __uint_as_float(u & 0xffff0000u); }
__device__ __forceinline__ float b2f(u16 v){ return __uint_as_float(((unsigned)v)<<16); }
__device__ __forceinline__ void ld8(const float* __restrict__ p, float* f){
  const float4 a = ((const float4*)p)[0];
  const float4 b = ((const float4*)p)[1];
  f[0]=a.x; f[1]=a.y; f[2]=a.z; f[3]=a.w;
  f[4]=b.x; f[5]=b.y; f[6]=b.z; f[7]=b.w;
}
__device__ __forceinline__ bf16x8 frag8(const float* __restrict__ p){
  float f[8]; ld8(p, f);
  bf16x8 r;
  #pragma unroll
  for (int j=0;j<8;++j) r[j] = (__bf16)f[j];
  return r;
}
__device__ __forceinline__ void unpk4u(uint4 u, float* f){
  f[0]=blo(u.x); f[1]=bhi(u.x);
  f[2]=blo(u.y); f[3]=bhi(u.y);
  f[4]=blo(u.z); f[5]=bhi(u.z);
  f[6]=blo(u.w); f[7]=bhi(u.w);
}

// ---------------- diagnostic marker (fp32 out) ----------------
__global__ __launch_bounds__(256) void k_marker(float* __restrict__ out, int n, float val){
  const int i = blockIdx.x*256 + threadIdx.x;
  if (i < n) out[i] = val;
}

// ---------------- slots init: mu + sigma * noise ----------------
__global__ __launch_bounds__(256) void k_init_slots(
  const float* __restrict__ mu, const float* __restrict__ sigma,
  const float* __restrict__ noise, float* __restrict__ slots)
{
  const int idx = blockIdx.x*256 + threadIdx.x;   // grid 56*256 = 14336 exact
  const int d = idx & 63;
  slots[idx] = mu[d] + sigma[d] * noise[idx];
}

// ---------------- per-iter: q = ln(slots)@Wq^T + bq; zero accumulators ----------------
__global__ __launch_bounds__(256) void k_qln_zero(
  const float* __restrict__ slots, const float* __restrict__ Wq, const float* __restrict__ bq,
  const float* __restrict__ g_sl, const float* __restrict__ b_sl,
  float* __restrict__ qout, float* __restrict__ num, float* __restrict__ den)
{
  const int tid = blockIdx.x*256 + threadIdx.x;    // grid 56*256 = 14336 exact
  num[tid] = 0.f;
  if (tid < 224) den[tid] = 0.f;
  const int ri = tid >> 6, lane = tid & 63;
  const float xv = slots[ri*64 + lane];
  float s = xv, ss = xv*xv;
  #pragma unroll
  for (int off=1; off<64; off<<=1){ s += __shfl_xor(s,off); ss += __shfl_xor(ss,off); }
  const float mean = s*(1.f/64.f);
  const float rstd = rsqrtf(ss*(1.f/64.f) - mean*mean + 1e-5f);
  const float sn = (xv-mean)*rstd*g_sl[lane] + b_sl[lane];
  float acc = 0.f;
  for (int d8=0; d8<8; ++d8){
    float wf[8]; ld8(Wq + lane*64 + d8*8, wf);
    #pragma unroll
    for (int j=0;j<8;++j) acc += __shfl(sn, d8*8+j) * wf[j];
  }
  qout[ri*64+lane] = acc + bq[lane];
}

// ================= FAST PATH: precompute k + chunk-transposed v =================
// k_kv: one block = 64 keys. LN(x) -> MFMA -> k[b*N+key][dim] bf16 (row-major)
// and vc[((b*2048 + key/8)*64 + dim)*8 + key%8] bf16 (chunk-transposed).
__global__ __launch_bounds__(256) void k_kv(
  const float* __restrict__ x,
  const float* __restrict__ Wk, const float* __restrict__ bk,
  const float* __restrict__ Wv, const float* __restrict__ bv,
  const float* __restrict__ g_in, const float* __restrict__ b_in,
  u16* __restrict__ kout, u16* __restrict__ vc)
{
  __shared__ __align__(16) u16 kt[64*72];   // 9.2 KB (72 pad: 16B-aligned rows)
  __shared__ __align__(16) u16 vt[64*72];   // 9.2 KB
  const int t = threadIdx.x, wid = t>>6, lane = t&63;
  const int m = lane&15, q4 = lane>>4;
  float gf[16], bfv[16];
  ld8(g_in + q4*8, gf);  ld8(g_in + 32 + q4*8, gf+8);
  ld8(b_in + q4*8, bfv); ld8(b_in + 32 + q4*8, bfv+8);
  // LN of this wave's 16 rows (row = wid*16 + m)
  const long row = (long)blockIdx.x*64 + wid*16 + m;
  const float* xr = x + row*64;
  float xf[16];
  ld8(xr + q4*8, xf); ld8(xr + 32 + q4*8, xf+8);
  float s=0.f, ss=0.f;
  #pragma unroll
  for (int i=0;i<16;++i){ s += xf[i]; ss += xf[i]*xf[i]; }
  s  += __shfl_xor(s,16);  s  += __shfl_xor(s,32);
  ss += __shfl_xor(ss,16); ss += __shfl_xor(ss,32);
  const float mean = s*(1.f/64.f);
  const float rstd = rsqrtf(ss*(1.f/64.f) - mean*mean + 1e-5f);
  bf16x8 a0, a1;
  #pragma unroll
  for (int j=0;j<8;++j){
    a0[j] = (__bf16)((xf[j]  -mean)*rstd*gf[j]   + bfv[j]);
    a1[j] = (__bf16)((xf[8+j]-mean)*rstd*gf[8+j] + bfv[8+j]);
  }
  #pragma unroll
  for (int sel=0; sel<2; ++sel){
    const float* W  = sel ? Wv : Wk;
    const float* bb = sel ? bv : bk;
    u16* tl         = sel ? vt : kt;
    #pragma unroll
    for (int cg=0; cg<4; ++cg){
      const int n = cg*16 + m;
      bf16x8 w0 = frag8(W + n*64 + q4*8);
      bf16x8 w1 = frag8(W + n*64 + 32 + q4*8);
      const float bc = bb[n];
      f32x4 acc = {0.f,0.f,0.f,0.f};
      acc = __builtin_amdgcn_mfma_f32_16x16x32_bf16(a0, w0, acc, 0,0,0);
      acc = __builtin_amdgcn_mfma_f32_16x16x32_bf16(a1, w1, acc, 0,0,0);
      #pragma unroll
      for (int r=0;r<4;++r)
        tl[(wid*16 + q4*4 + r)*72 + cg*16 + m] = f2b(acc[r] + bc);
    }
  }
  __syncthreads();
  // k out: coalesced row-major
  {
    const int r = t>>2, seg = t&3;
    const uint4 p0 = *(const uint4*)&kt[r*72 + seg*16];
    const uint4 p1 = *(const uint4*)&kt[r*72 + seg*16 + 8];
    u16* gp = kout + ((long)blockIdx.x*64 + r)*64 + seg*16;
    ((uint4*)gp)[0] = p0; ((uint4*)gp)[1] = p1;
  }
  // vc out: chunk-transposed [b][key/8][dim][8]
  {
    const int d = t>>2, kseg = t&3;
    const int b = blockIdx.x >> 8;
    const int n0 = (blockIdx.x & 255)*64 + kseg*16;   // key within batch
    unsigned pk[8];
    #pragma unroll
    for (int c=0;c<16;c+=2){
      const unsigned lo = vt[(kseg*16 + c  )*72 + d];
      const unsigned hi = vt[(kseg*16 + c+1)*72 + d];
      pk[c>>1] = lo | (hi<<16);
    }
    const long jc0 = (long)b*2048 + (n0>>3);
    u16* g0 = vc + (jc0*64 + d)*8;
    u16* g1 = vc + ((jc0+1)*64 + d)*8;
    *((uint4*)g0) = make_uint4(pk[0],pk[1],pk[2],pk[3]);
    *((uint4*)g1) = make_uint4(pk[4],pk[5],pk[6],pk[7]);
  }
}

// k_attn2: per-iter streaming attention from precomputed k + vc.
// grid = 32 b x 32 ch (512 keys/block, 2 tiles of 256). block=256.
__global__ __launch_bounds__(256) void k_attn2(
  const u16* __restrict__ kbuf, const u16* __restrict__ vc,
  const float* __restrict__ qbuf, float* __restrict__ num, float* __restrict__ den)
{
  __shared__ __align__(16) float qs[448];
  __shared__ __align__(16) u16   atb[7*256];   // bf16 attn weights
  __shared__ float den_s[7];
  const int t = threadIdx.x;
  const int b = blockIdx.x >> 5, ch = blockIdx.x & 31;
  for (int i=t;i<448;i+=256) qs[i] = qbuf[b*448+i];
  if (t<7) den_s[t] = 0.f;
  const int wid = t>>6, lane = t&63;
  const int i0 = wid*2, i1 = wid*2+1;   // wid 3 -> only slot 6
  float n0 = 0.f, n1 = 0.f;
  __syncthreads();

  for (int tl=0; tl<2; ++tl){
    // ---- phase A: thread t owns key ch*512 + tl*256 + t ----
    {
      const int key = ch*512 + tl*256 + t;
      const u16* kr = kbuf + ((long)b*N_ + key)*64;
      uint4 kw[8];
      #pragma unroll
      for (int c=0;c<8;++c) kw[c] = ((const uint4*)kr)[c];
      float acc[7];
      #pragma unroll
      for (int i=0;i<7;++i) acc[i] = 0.f;
      const unsigned* kwu = (const unsigned*)kw;
      #pragma unroll
      for (int w8=0; w8<8; ++w8){
        float kf[8];
        kf[0]=blo(kwu[w8*4+0]); kf[1]=bhi(kwu[w8*4+0]);
        kf[2]=blo(kwu[w8*4+1]); kf[3]=bhi(kwu[w8*4+1]);
        kf[4]=blo(kwu[w8*4+2]); kf[5]=bhi(kwu[w8*4+2]);
        kf[6]=blo(kwu[w8*4+3]); kf[7]=bhi(kwu[w8*4+3]);
        #pragma unroll
        for (int i=0;i<7;++i){
          const float4 qa = *(const float4*)&qs[i*64 + w8*8];
          const float4 qb = *(const float4*)&qs[i*64 + w8*8 + 4];
          acc[i] += kf[0]*qa.x + kf[1]*qa.y + kf[2]*qa.z + kf[3]*qa.w
                  + kf[4]*qb.x + kf[5]*qb.y + kf[6]*qb.z + kf[7]*qb.w;
        }
      }
      float mx = -1e30f;
      #pragma unroll
      for (int i=0;i<7;++i){ acc[i] *= SCALE_; mx = fmaxf(mx, acc[i]); }
      float e[7]; float sum = 0.f;
      #pragma unroll
      for (int i=0;i<7;++i){ e[i] = __expf(acc[i]-mx); sum += e[i]; }
      const float inv = 1.f/sum;
      float dsum[7];
      #pragma unroll
      for (int i=0;i<7;++i){
        const float av = e[i]*inv + 1e-8f;
        const u16 rb = f2b(av);
        atb[i*256 + t] = rb;
        dsum[i] = b2f(rb);          // den from the SAME rounded weights as num
      }
      #pragma unroll
      for (int i=0;i<7;++i){
        #pragma unroll
        for (int off=1; off<64; off<<=1) dsum[i] += __shfl_xor(dsum[i], off);
      }
      if (lane == 0){
        #pragma unroll
        for (int i=0;i<7;++i) atomicAdd(&den_s[i], dsum[i]);
      }
    }
    __syncthreads();   // atb + den ready
    // ---- phase B: lane = dim, wave = slots {i0,i1}; 32 chunks of 8 keys ----
    {
      const long cell0 = ((long)b*2048 + ch*64 + tl*32);
      for (int it=0; it<32; ++it){
        const uint4 vv = *(const uint4*)(vc + ((cell0 + it)*64 + lane)*8);
        float vf[8]; unpk4u(vv, vf);
        const uint4 aw0 = *(const uint4*)&atb[i0*256 + it*8];
        float a0f[8]; unpk4u(aw0, a0f);
        #pragma unroll
        for (int e=0;e<8;++e) n0 += a0f[e]*vf[e];
        if (i1 < 7){
          const uint4 aw1 = *(const uint4*)&atb[i1*256 + it*8];
          float a1f[8]; unpk4u(aw1, a1f);
          #pragma unroll
          for (int e=0;e<8;++e) n1 += a1f[e]*vf[e];
        }
      }
    }
    __syncthreads();   // atb free for next tile's phase A
  }
  atomicAdd(&num[(b*7+i0)*64 + lane], n0);
  if (i1 < 7) atomicAdd(&num[(b*7+i1)*64 + lane], n1);
  if (t < 7) atomicAdd(&den[b*7+t], den_s[t]);
}

// ================= FALLBACK: fused attention (verified, round-6) =================
__global__ __launch_bounds__(256) void k_attn_fused(
  const float* __restrict__ x,
  const float* __restrict__ Wk, const float* __restrict__ bk,
  const float* __restrict__ Wv, const float* __restrict__ bv,
  const float* __restrict__ g_in, const float* __restrict__ b_in,
  const float* __restrict__ qbuf, float* __restrict__ num, float* __restrict__ den)
{
  __shared__ __align__(16) u16   tile[TILE*TPAD];
  __shared__ __align__(16) float qs[7*64];
  __shared__ __align__(16) float at[7*TILE];
  const int t = threadIdx.x;
  const int b = blockIdx.x >> 6, ch = blockIdx.x & 63;
  for (int i=t; i<448; i+=256) qs[i] = qbuf[b*448 + i];
  const int wid = t>>6, lane = t&63;
  const int m = lane & 15, q4 = lane >> 4;
  float gf[16], bfv[16];
  ld8(g_in + q4*8, gf);  ld8(g_in + 32 + q4*8, gf+8);
  ld8(b_in + q4*8, bfv); ld8(b_in + 32 + q4*8, bfv+8);
  const int i0 = wid*2, i1 = wid*2+1;
  float n0=0.f, n1=0.f, d0=0.f, d1=0.f;

  for (int tl=0; tl<2; ++tl){
    const long j0 = (long)ch*256 + tl*TILE;
    const long rowbase = (long)b*N_ + j0 + (long)wid*32;
    __syncthreads();
    bf16x8 af[2][2];
    #pragma unroll
    for (int rg=0; rg<2; ++rg){
      const float* xr = x + (rowbase + rg*16 + m)*64;
      float xf[16];
      ld8(xr + q4*8, xf); ld8(xr + 32 + q4*8, xf+8);
      float s=0.f, ss=0.f;
      #pragma unroll
      for (int i=0;i<16;++i){ s += xf[i]; ss += xf[i]*xf[i]; }
      s  += __shfl_xor(s,16);  s  += __shfl_xor(s,32);
      ss += __shfl_xor(ss,16); ss += __shfl_xor(ss,32);
      const float mean = s*(1.f/64.f);
      const float rstd = rsqrtf(ss*(1.f/64.f) - mean*mean + 1e-5f);
      #pragma unroll
      for (int j=0;j<8;++j){
        af[rg][0][j] = (__bf16)((xf[j]  -mean)*rstd*gf[j]   + bfv[j]);
        af[rg][1][j] = (__bf16)((xf[8+j]-mean)*rstd*gf[8+j] + bfv[8+j]);
      }
    }
    {
      bf16x8 w0[4], w1[4]; float bc[4];
      #pragma unroll
      for (int cg=0; cg<4; ++cg){
        const int n = cg*16 + m;
        w0[cg] = frag8(Wk + n*64 + q4*8);
        w1[cg] = frag8(Wk + n*64 + 32 + q4*8);
        bc[cg] = bk[n];
      }
      #pragma unroll
      for (int rg=0; rg<2; ++rg){
        #pragma unroll
        for (int cg=0; cg<4; ++cg){
          f32x4 acc = {0.f,0.f,0.f,0.f};
          acc = __builtin_amdgcn_mfma_f32_16x16x32_bf16(af[rg][0], w0[cg], acc, 0,0,0);
          acc = __builtin_amdgcn_mfma_f32_16x16x32_bf16(af[rg][1], w1[cg], acc, 0,0,0);
          const int col = cg*16 + m;
          #pragma unroll
          for (int r=0;r<4;++r)
            tile[(wid*32 + rg*16 + q4*4 + r)*TPAD + col] = f2b(acc[r] + bc[cg]);
        }
      }
    }
    __syncthreads();
    if (t < TILE){
      float acc[7];
      #pragma unroll
      for (int i=0;i<7;++i) acc[i]=0.f;
      const unsigned* krow = (const unsigned*)&tile[t*TPAD];
      for (int wq=0; wq<8; ++wq){
        const unsigned k0 = krow[wq*4+0], k1 = krow[wq*4+1], k2 = krow[wq*4+2], k3 = krow[wq*4+3];
        float kf[8];
        kf[0]=blo(k0); kf[1]=bhi(k0); kf[2]=blo(k1); kf[3]=bhi(k1);
        kf[4]=blo(k2); kf[5]=bhi(k2); kf[6]=blo(k3); kf[7]=bhi(k3);
        #pragma unroll
        for (int i=0;i<7;++i){
          const float4 qa = *(const float4*)&qs[i*64 + wq*8];
          const float4 qb = *(const float4*)&qs[i*64 + wq*8 + 4];
          acc[i] += kf[0]*qa.x + kf[1]*qa.y + kf[2]*qa.z + kf[3]*qa.w
                  + kf[4]*qb.x + kf[5]*qb.y + kf[6]*qb.z + kf[7]*qb.w;
        }
      }
      float mx = -1e30f;
      #pragma unroll
      for (int i=0;i<7;++i){ acc[i] *= SCALE_; mx = fmaxf(mx, acc[i]); }
      float e[7]; float sum = 0.f;
      #pragma unroll
      for (int i=0;i<7;++i){ e[i] = __expf(acc[i]-mx); sum += e[i]; }
      const float inv = 1.f/sum;
      #pragma unroll
      for (int i=0;i<7;++i) at[i*TILE + t] = e[i]*inv + 1e-8f;
    }
    __syncthreads();
    {
      bf16x8 w0[4], w1[4]; float bc[4];
      #pragma unroll
      for (int cg=0; cg<4; ++cg){
        const int n = cg*16 + m;
        w0[cg] = frag8(Wv + n*64 + q4*8);
        w1[cg] = frag8(Wv + n*64 + 32 + q4*8);
        bc[cg] = bv[n];
      }
      #pragma unroll
      for (int rg=0; rg<2; ++rg){
        #pragma unroll
        for (int cg=0; cg<4; ++cg){
          f32x4 acc = {0.f,0.f,0.f,0.f};
          acc = __builtin_amdgcn_mfma_f32_16x16x32_bf16(af[rg][0], w0[cg], acc, 0,0,0);
          acc = __builtin_amdgcn_mfma_f32_16x16x32_bf16(af[rg][1], w1[cg], acc, 0,0,0);
          const int col = cg*16 + m;
          #pragma unroll
          for (int r=0;r<4;++r)
            tile[(wid*32 + rg*16 + q4*4 + r)*TPAD + col] = f2b(acc[r] + bc[cg]);
        }
      }
    }
    __syncthreads();
    #pragma unroll 4
    for (int j=0;j<TILE;++j){
      const unsigned vw = ((const unsigned*)&tile[j*TPAD])[lane>>1];
      const float vf = (lane&1) ? bhi(vw) : blo(vw);
      const float a0v = at[i0*TILE+j];
      n0 += a0v*vf; d0 += a0v;
      if (i1 < 7){ const float a1v = at[i1*TILE+j]; n1 += a1v*vf; d1 += a1v; }
    }
  }
  atomicAdd(&num[(b*7+i0)*64 + lane], n0);
  if (lane==0) atomicAdd(&den[b*7+i0], d0);
  if (i1 < 7){
    atomicAdd(&num[(b*7+i1)*64 + lane], n1);
    if (lane==0) atomicAdd(&den[b*7+i1], d1);
  }
}

// ---------------- per-iter: updates -> GRU -> residual MLP ----------------
__global__ __launch_bounds__(256) void k_gru_mlp(
  const float* __restrict__ num, const float* __restrict__ den, float* __restrict__ slots,
  const float* __restrict__ Wih, const float* __restrict__ Whh,
  const float* __restrict__ bih, const float* __restrict__ bhh,
  const float* __restrict__ mW1, const float* __restrict__ mb1,
  const float* __restrict__ mW2, const float* __restrict__ mb2,
  const float* __restrict__ g_ml, const float* __restrict__ b_ml,
  float* __restrict__ outp, const int write_out)
{
  const int tid = blockIdx.x*256 + threadIdx.x;  // grid 56*256: 224 waves = 224 rows
  const int ri = tid>>6, lane = tid&63;
  const float dn = den[ri];
  const float u = (dn > 0.f) ? (num[ri*64+lane] / dn) : 0.f;
  const float h = slots[ri*64+lane];
  float air=0,aiz=0,ain=0,ahr=0,ahz=0,ahn=0;
  for (int d8=0; d8<8; ++d8){
    float fir[8],fiz[8],fin[8],fhr[8],fhz[8],fhn[8];
    ld8(Wih + (      lane)*64 + d8*8, fir);
    ld8(Wih + ( 64 + lane)*64 + d8*8, fiz);
    ld8(Wih + (128 + lane)*64 + d8*8, fin);
    ld8(Whh + (      lane)*64 + d8*8, fhr);
    ld8(Whh + ( 64 + lane)*64 + d8*8, fhz);
    ld8(Whh + (128 + lane)*64 + d8*8, fhn);
    #pragma unroll
    for (int j=0;j<8;++j){
      const float ud = __shfl(u, d8*8+j);
      const float hd = __shfl(h, d8*8+j);
      air += ud*fir[j]; aiz += ud*fiz[j]; ain += ud*fin[j];
      ahr += hd*fhr[j]; ahz += hd*fhz[j]; ahn += hd*fhn[j];
    }
  }
  air += bih[lane]; aiz += bih[64+lane]; ain += bih[128+lane];
  ahr += bhh[lane]; ahz += bhh[64+lane]; ahn += bhh[128+lane];
  const float r = 1.f/(1.f + __expf(-(air+ahr)));
  const float z = 1.f/(1.f + __expf(-(aiz+ahz)));
  const float n = tanhf(ain + r*ahn);
  const float sv = (1.f-z)*n + z*h;
  float s=sv, ss=sv*sv;
  #pragma unroll
  for (int off=1; off<64; off<<=1){ s += __shfl_xor(s,off); ss += __shfl_xor(ss,off); }
  const float mean = s*(1.f/64.f);
  const float rstd = rsqrtf(ss*(1.f/64.f) - mean*mean + 1e-5f);
  const float m = (sv-mean)*rstd*g_ml[lane] + b_ml[lane];
  float h1a=0.f, h1b=0.f;
  for (int d8=0; d8<8; ++d8){
    float f1[8], f2[8];
    ld8(mW1 + (     lane)*64 + d8*8, f1);
    ld8(mW1 + (64 + lane)*64 + d8*8, f2);
    #pragma unroll
    for (int j=0;j<8;++j){
      const float md = __shfl(m, d8*8+j);
      h1a += md*f1[j]; h1b += md*f2[j];
    }
  }
  h1a = fmaxf(h1a + mb1[lane], 0.f);
  h1b = fmaxf(h1b + mb1[64+lane], 0.f);
  float o = 0.f;
  for (int h8=0; h8<8; ++h8){
    float fa[8], fb[8];
    ld8(mW2 + lane*128 + h8*8, fa);
    ld8(mW2 + lane*128 + 64 + h8*8, fb);
    #pragma unroll
    for (int j=0;j<8;++j){
      o += __shfl(h1a, h8*8+j)*fa[j] + __shfl(h1b, h8*8+j)*fb[j];
    }
  }
  o += mb2[lane];
  const float res = sv + o;
  slots[ri*64+lane] = res;
  if (write_out) outp[ri*64+lane] = res;
}

extern "C" void kernel_launch(void* const* d_in, const int* in_sizes, int n_in,
                              void* d_out, int out_size, void* d_ws, size_t ws_size,
                              hipStream_t stream)
{
  float* outp = (float*)d_out;
  static const int EXP[24] = {33554432,14336,64,64, 4096,64, 4096,64, 4096,64,
                              12288,12288,192,192, 8192,128, 8192,64,
                              64,64, 64,64, 64,64};
  if (n_in != 24){ k_marker<<<56,256,0,stream>>>(outp, out_size, 30.f); return; }
  for (int i=0;i<24;++i)
    if (in_sizes[i] != EXP[i]){ k_marker<<<56,256,0,stream>>>(outp, out_size, 40.f+(float)i); return; }
  if (out_size != 14336){ k_marker<<<56,256,0,stream>>>(outp, out_size, 33.f); return; }
  if (ws_size < 200000){ k_marker<<<56,256,0,stream>>>(outp, out_size, 35.f); return; }

  const float* inputs = (const float*)d_in[0];
  const float* noise  = (const float*)d_in[1];
  const float* mu     = (const float*)d_in[2];
  const float* sigma  = (const float*)d_in[3];
  const float* Wq  = (const float*)d_in[4];  const float* bq  = (const float*)d_in[5];
  const float* Wk  = (const float*)d_in[6];  const float* bk  = (const float*)d_in[7];
  const float* Wv  = (const float*)d_in[8];  const float* bv  = (const float*)d_in[9];
  const float* Wih = (const float*)d_in[10]; const float* Whh = (const float*)d_in[11];
  const float* bih = (const float*)d_in[12]; const float* bhh = (const float*)d_in[13];
  const float* mW1 = (const float*)d_in[14]; const float* mb1 = (const float*)d_in[15];
  const float* mW2 = (const float*)d_in[16]; const float* mb2 = (const float*)d_in[17];
  const float* g_in = (const float*)d_in[18]; const float* b_in = (const float*)d_in[19];
  const float* g_sl = (const float*)d_in[20]; const float* b_sl = (const float*)d_in[21];
  const float* g_ml = (const float*)d_in[22]; const float* b_ml = (const float*)d_in[23];

  char* ws = (char*)d_ws;
  float* slots = (float*)ws;                         // 14336 f
  float* qbuf  = (float*)(ws + 57344);               // 14336 f
  float* num   = (float*)(ws + 114688);              // 14336 f
  float* den   = (float*)(ws + 172032);              // 224 f
  u16* kbuf    = (u16*)(ws + 200704);                // 33.5M bf16 (67.1 MB)
  u16* vc      = (u16*)(ws + 200704 + 67108864);     // 33.5M bf16 (67.1 MB)
  const bool fast = (ws_size >= (size_t)200704 + 2ull*67108864ull);

  k_init_slots<<<56,256,0,stream>>>(mu, sigma, noise, slots);
  if (fast)
    k_kv<<<8192,256,0,stream>>>(inputs, Wk, bk, Wv, bv, g_in, b_in, kbuf, vc);
  for (int it=0; it<3; ++it){
    k_qln_zero<<<56,256,0,stream>>>(slots, Wq, bq, g_sl, b_sl, qbuf, num, den);
    if (fast)
      k_attn2<<<1024,256,0,stream>>>(kbuf, vc, qbuf, num, den);
    else
      k_attn_fused<<<2048,256,0,stream>>>(inputs, Wk, bk, Wv, bv, g_in, b_in, qbuf, num, den);
    k_gru_mlp<<<56,256,0,stream>>>(num, den, slots, Wih, Whh, bih, bhh,
                                   mW1, mb1, mW2, mb2, g_ml, b_ml,
                                   outp, it==2 ? 1 : 0);
  }
}